// Round 3
// baseline (1415.177 us; speedup 1.0000x reference)
//
#include <hip/hip_runtime.h>
#include <math.h>

// Soft-Viterbi structured decoding: B=32, T=512, N=128, fp32.
// Round 3: eliminate the LDS-broadcast bottleneck (rounds 1-2: ~64 wide LDS
// reads/step through the shared per-CU LDS pipe ≈ 768+ cyc/step, plus bank
// conflicts). New structure:
//   * Every wave redundantly carries the FULL 128-float alpha/q vector in
//     registers (lane l holds states 2l,2l+1; identical across waves).
//   * Dot products: wave w computes partials for output block 64*(w>>1)+lane
//     over k-half [64*(w&1), 64*(w&1)+64). The broadcast of alpha[k] is
//     v_readlane (uniform index per wave = 32*(w&1)+k) -> VALU-pipe, private
//     per SIMD, parallel across the 4 waves. 64 readlane + 64 FMA per lane.
//   * LDS per step: only the partial-sum exchange: 4x ds_write_b32 +
//     8x ds_read_b64 + 2 bcast b32 (~12 instrs), ping-pong buffers ->
//     ONE barrier/step.
//   * Normalizer r_t = rcp(Z_raw_t[0]); stored in sarr[] (LDS). r cancels
//     exactly in the backward reconstruction q[n] = p*d*r/alpha~ = p/Z, so
//     approximate v_rcp introduces no inconsistency.
// Forward: alpha~_t[n] = d_t[n] * r_t * Z_t[n], Z_t[n] = sum_p T[p,n] alpha~_{t-1}[p]
// Backward: p_t[m] = alpha~_t[m] * sum_n T[m,n] q[n],
//           q[n] = p_{t+1}[n] * d_{t+1}[n] * sarr[t+1] / alpha~_{t+1}[n]
// alpha~ history stashed in out[b][t][:] (overwritten by p_t in backward).

#define TT 512
#define BB 32
#define NN 128
#define EPSC 1e-10f

__device__ __forceinline__ float rdl(float v, int sl) {
  return __uint_as_float(__builtin_amdgcn_readlane(__float_as_uint(v), sl));
}
__device__ __forceinline__ float rcpf(float v) { return __builtin_amdgcn_rcpf(v); }

__global__ __launch_bounds__(256, 1)
void soft_viterbi_kernel(const float* __restrict__ trans,
                         const float* __restrict__ emis,
                         const float* __restrict__ prior,
                         float* __restrict__ out) {
  const int b    = blockIdx.x;
  const int tid  = threadIdx.x;
  const int w    = tid >> 6;
  const int lane = tid & 63;
  const int h    = w & 1;                       // k-half this wave sums
  const int pr_  = w >> 1;                      // output block (0: states 0-63, 1: 64-127)
  const int n_own = 64 * pr_ + lane;            // output state for this lane's dot
  const int hb   = __builtin_amdgcn_readfirstlane(32 * h);  // readlane base (SGPR)
  const int ps   = lane >> 5;                   // pair block of carried states 2l,2l+1
  const int sl   = (2 * lane) & 63;             // index within pair block

  __shared__ __align__(16) float part[2][2][136];  // [pingpong][pair][half*68 + idx]
  __shared__ float sarr[TT];                       // r_t for backward
  __shared__ __align__(16) float red[NN];          // 1/rowsum

  const float2* em2 = (const float2*)emis + (size_t)b * TT * 64;
  float2* out2 = (float2*)out + (size_t)b * TT * 64;

  // ---- 1/rowsum of clipped transition ----
  if (tid < NN) {
    const float4* row = (const float4*)(trans + tid * NN);
    float s = 0.f;
    #pragma unroll 8
    for (int j = 0; j < NN / 4; ++j) {
      float4 v = row[j];
      s += fmaxf(v.x, EPSC) + fmaxf(v.y, EPSC) + fmaxf(v.z, EPSC) + fmaxf(v.w, EPSC);
    }
    red[tid] = 1.0f / s;
  }
  __syncthreads();

  // ---- forward fragment: tf[k] = Tn[64h+k][n_own] ----
  float tf[64];
  #pragma unroll 8
  for (int k = 0; k < 64; ++k) {
    const int p = 64 * h + k;
    tf[k] = fmaxf(trans[p * NN + n_own], EPSC) * red[p];
  }
  // ---- backward fragment: tb[k] = Tn[n_own][64h+k] ----
  float tb[64];
  {
    const float inv = red[n_own];
    const float4* r = (const float4*)(trans + n_own * NN + 64 * h);
    #pragma unroll
    for (int k = 0; k < 16; ++k) {
      float4 v = r[k];
      tb[4*k+0] = fmaxf(v.x, EPSC) * inv;
      tb[4*k+1] = fmaxf(v.y, EPSC) * inv;
      tb[4*k+2] = fmaxf(v.z, EPSC) * inv;
      tb[4*k+3] = fmaxf(v.w, EPSC) * inv;
    }
  }

  // ---- alpha~_0 = prior_norm * exp(em_0), lane-local, replicated across waves ----
  float2 pv = ((const float2*)prior)[lane];
  float p0v = fmaxf(pv.x, EPSC), p1v = fmaxf(pv.y, EPSC);
  float psum = p0v + p1v;
  #pragma unroll
  for (int m = 1; m < 64; m <<= 1) psum += __shfl_xor(psum, m, 64);
  const float pinv = rcpf(psum);
  float2 e0 = em2[lane];
  float a0 = p0v * pinv * __expf(e0.x);
  float a1 = p1v * pinv * __expf(e0.y);
  if (w == 0) out2[lane] = make_float2(a0, a1);

  // em pipeline: d = exp(em[t]) ready at iteration t; em_hold = em[t+1]
  float2 emA = em2[64 + lane];        // em[1]
  float2 em_hold = em2[128 + lane];   // em[2]
  float d0 = __expf(emA.x), d1 = __expf(emA.y);
  float rinv_last = 1.f;

  // ================= forward =================
  for (int t = 1; t < TT; ++t) {
    // partial dot over half h: c = sum_k tf[..] * alpha~[64h + ..] via readlane
    float c0 = 0.f, c1 = 0.f, c2 = 0.f, c3 = 0.f;
    #pragma unroll
    for (int k = 0; k < 32; k += 2) {
      float s0 = rdl(a0, hb + k), s1 = rdl(a1, hb + k);
      c0 = fmaf(s0, tf[2*k],   c0);
      c1 = fmaf(s1, tf[2*k+1], c1);
      float s2 = rdl(a0, hb + k + 1), s3 = rdl(a1, hb + k + 1);
      c2 = fmaf(s2, tf[2*k+2], c2);
      c3 = fmaf(s3, tf[2*k+3], c3);
    }
    const int buf = t & 1;
    part[buf][pr_][h * 68 + lane] = (c0 + c2) + (c1 + c3);
    // off-chain prefetch
    const int tp = (t + 2 < TT) ? t + 2 : TT - 1;
    float2 em_pf = em2[tp * 64 + lane];
    __syncthreads();
    float2 pA = *(const float2*)&part[buf][ps][sl];
    float2 pB = *(const float2*)&part[buf][ps][68 + sl];
    const float raw0 = part[buf][0][0] + part[buf][0][68];
    const float rinv = rcpf(raw0);
    if (tid == 0) sarr[t] = rinv;
    rinv_last = rinv;
    a0 = (pA.x + pB.x) * (d0 * rinv);
    a1 = (pA.y + pB.y) * (d1 * rinv);
    if (w == 0 && t < TT - 1) out2[t * 64 + lane] = make_float2(a0, a1);
    d0 = __expf(em_hold.x); d1 = __expf(em_hold.y);   // d_{t+1}, off-chain
    em_hold = em_pf;
  }
  // post-loop: d0,d1 = exp(em[TT-1]) = d_{T-1}; rinv_last = r_{TT-1}

  // ================= final softmax (in-wave, replicated) =================
  float tot = a0 + a1;
  #pragma unroll
  for (int m = 1; m < 64; m <<= 1) tot += __shfl_xor(tot, m, 64);
  const float it = rcpf(tot);
  float q0 = a0 * it, q1 = a1 * it;                 // p_{T-1}
  if (w == 0) out2[(TT - 1) * 64 + lane] = make_float2(q0, q1);

  // q for first backward dot: q = p_{T-1} * d_{T-1} * r_{T-1} / alpha~_{T-1}
  q0 = q0 * (d0 * rinv_last * rcpf(a0));
  q1 = q1 * (d1 * rinv_last * rcpf(a1));

  // backward prefetch pipeline
  float2 ec_cur = out2[(TT - 2) * 64 + lane];       // alpha~_{TT-2}
  float2 ec_nxt = out2[(TT - 3) * 64 + lane];       // alpha~_{TT-3}
  float2 emb_c  = em2[(TT - 2) * 64 + lane];        // em[TT-2]
  float2 emb_n  = em2[(TT - 3) * 64 + lane];        // em[TT-3]
  float db0 = __expf(emb_c.x), db1 = __expf(emb_c.y);
  float sr_c = sarr[TT - 2];                        // visible: barriers since fwd write

  // ================= backward =================
  for (int t = TT - 2; t >= 0; --t) {
    // partial dot: c = sum_k tb[..] * q[64h + ..]
    float c0 = 0.f, c1 = 0.f, c2 = 0.f, c3 = 0.f;
    #pragma unroll
    for (int k = 0; k < 32; k += 2) {
      float s0 = rdl(q0, hb + k), s1 = rdl(q1, hb + k);
      c0 = fmaf(s0, tb[2*k],   c0);
      c1 = fmaf(s1, tb[2*k+1], c1);
      float s2 = rdl(q0, hb + k + 1), s3 = rdl(q1, hb + k + 1);
      c2 = fmaf(s2, tb[2*k+2], c2);
      c3 = fmaf(s3, tb[2*k+3], c3);
    }
    const int buf = t & 1;
    part[buf][pr_][h * 68 + lane] = (c0 + c2) + (c1 + c3);
    // off-chain: g for q_next (all inputs prefetched)
    const float g0 = db0 * sr_c * rcpf(ec_cur.x);
    const float g1 = db1 * sr_c * rcpf(ec_cur.y);
    const int tp = (t >= 2) ? t - 2 : 0;
    float2 ec_pf = out2[tp * 64 + lane];
    float2 em_pf = em2[tp * 64 + lane];
    const int ts = (t >= 1) ? t - 1 : 0;
    const float sr_n = sarr[ts];
    __syncthreads();
    float2 pA = *(const float2*)&part[buf][ps][sl];
    float2 pB = *(const float2*)&part[buf][ps][68 + sl];
    const float p0 = ec_cur.x * (pA.x + pB.x);
    const float p1 = ec_cur.y * (pA.y + pB.y);
    if (w == 0) out2[t * 64 + lane] = make_float2(p0, p1);
    q0 = p0 * g0; q1 = p1 * g1;
    // rotate prefetch pipeline
    ec_cur = ec_nxt; ec_nxt = ec_pf;
    db0 = __expf(emb_n.x); db1 = __expf(emb_n.y);
    emb_n = em_pf;
    sr_c = sr_n;
  }
}

extern "C" void kernel_launch(void* const* d_in, const int* in_sizes, int n_in,
                              void* d_out, int out_size, void* d_ws, size_t ws_size,
                              hipStream_t stream) {
  (void)in_sizes; (void)n_in; (void)d_ws; (void)ws_size; (void)out_size;
  const float* trans = (const float*)d_in[0];
  const float* emis  = (const float*)d_in[1];
  const float* prior = (const float*)d_in[2];
  float* out = (float*)d_out;
  soft_viterbi_kernel<<<dim3(BB), dim3(256), 0, stream>>>(trans, emis, prior, out);
}

// Round 4
// 584.526 us; speedup vs baseline: 2.4211x; 2.4211x over previous
//
#include <hip/hip_runtime.h>
#include <math.h>

// Soft-Viterbi structured decoding: B=32, T=512, N=128, fp32.
// Round 4 = round 3 structure (readlane broadcast, one barrier/step) with the
// register-allocation bug fixed:
//   * tf[] fill loop FULLY unrolled (r3's "#pragma unroll 8" left a runtime
//     index -> tf/tb demoted to scratch -> VGPR_Count=60 and 1.4 ms).
//   * dot helpers templated on half-base so v_readlane gets an immediate
//     lane select (no per-instance s_add chain; lower SGPR pressure).
// Structure recap:
//   * Every wave redundantly carries the FULL 128-float alpha/q vector in
//     registers (lane l holds states 2l,2l+1; identical across waves).
//   * Wave w computes dot partials for output block 64*(w>>1)+lane over
//     k-half [64*(w&1), +64). Broadcast of alpha[k] via v_readlane (VALU,
//     per-SIMD, parallel across waves): 64 rdl + 64 FMA per lane per step.
//   * LDS per step: only the 2x64-float partial exchange, ping-ponged ->
//     ONE __syncthreads per step.
//   * Normalizer r_t = rcp(Z_raw[0]) (cancels exactly in backward).
// Forward: alpha~_t[n] = d_t[n] * r_t * Z_t[n], Z_t[n] = sum_p T[p,n] alpha~_{t-1}[p]
// Backward: p_t[m] = alpha~_t[m] * sum_n T[m,n] q[n],
//           q[n] = p_{t+1}[n] * d_{t+1}[n] * sarr[t+1] / alpha~_{t+1}[n]
// alpha~ history stashed in out[b][t][:] (overwritten by p_t in backward).

#define TT 512
#define BB 32
#define NN 128
#define EPSC 1e-10f

__device__ __forceinline__ float rdl(float v, int sl) {
  return __uint_as_float(__builtin_amdgcn_readlane(__float_as_uint(v), sl));
}
__device__ __forceinline__ float rcpf(float v) { return __builtin_amdgcn_rcpf(v); }

// Partial dot over one 64-state half: sum_k frag[2k]*alpha[64h+2k] + frag[2k+1]*alpha[64h+2k+1]
// B = 32*h (lane base, compile-time). va0/va1 carry states (2l, 2l+1).
template <int B>
__device__ __forceinline__ float dot_half(const float (&frag)[64], float va0, float va1) {
  float c0 = 0.f, c1 = 0.f, c2 = 0.f, c3 = 0.f;
  #pragma unroll
  for (int k = 0; k < 32; k += 2) {
    c0 = fmaf(rdl(va0, B + k),     frag[2 * k],     c0);
    c1 = fmaf(rdl(va1, B + k),     frag[2 * k + 1], c1);
    c2 = fmaf(rdl(va0, B + k + 1), frag[2 * k + 2], c2);
    c3 = fmaf(rdl(va1, B + k + 1), frag[2 * k + 3], c3);
  }
  return (c0 + c2) + (c1 + c3);
}

__global__ __launch_bounds__(256, 1)
void soft_viterbi_kernel(const float* __restrict__ trans,
                         const float* __restrict__ emis,
                         const float* __restrict__ prior,
                         float* __restrict__ out) {
  const int b    = blockIdx.x;
  const int tid  = threadIdx.x;
  const int w    = tid >> 6;
  const int lane = tid & 63;
  const int h    = w & 1;                       // k-half this wave sums
  const int pr_  = w >> 1;                      // output block (0: states 0-63, 1: 64-127)
  const int n_own = 64 * pr_ + lane;            // output state for this lane's dot
  const int ps   = lane >> 5;                   // pair block of carried states 2l,2l+1
  const int sl   = (2 * lane) & 63;             // index within pair block

  __shared__ __align__(16) float part[2][2][136];  // [pingpong][pair][half*68 + idx]
  __shared__ float sarr[TT];                       // r_t for backward
  __shared__ __align__(16) float red[NN];          // 1/rowsum

  const float2* em2 = (const float2*)emis + (size_t)b * TT * 64;
  float2* out2 = (float2*)out + (size_t)b * TT * 64;

  // ---- 1/rowsum of clipped transition ----
  if (tid < NN) {
    const float4* row = (const float4*)(trans + tid * NN);
    float s = 0.f;
    #pragma unroll 8
    for (int j = 0; j < NN / 4; ++j) {
      float4 v = row[j];
      s += fmaxf(v.x, EPSC) + fmaxf(v.y, EPSC) + fmaxf(v.z, EPSC) + fmaxf(v.w, EPSC);
    }
    red[tid] = 1.0f / s;
  }
  __syncthreads();

  // ---- forward fragment: tf[k] = Tn[64h+k][n_own]  (FULL unroll: keep in VGPRs!) ----
  float tf[64];
  {
    const float* tcol = trans + 64 * h * NN + n_own;
    const float* rrow = red + 64 * h;
    #pragma unroll
    for (int k = 0; k < 64; ++k) {
      tf[k] = fmaxf(tcol[k * NN], EPSC) * rrow[k];
    }
  }
  // ---- backward fragment: tb[k] = Tn[n_own][64h+k] ----
  float tb[64];
  {
    const float inv = red[n_own];
    const float4* r = (const float4*)(trans + n_own * NN + 64 * h);
    #pragma unroll
    for (int k = 0; k < 16; ++k) {
      float4 v = r[k];
      tb[4*k+0] = fmaxf(v.x, EPSC) * inv;
      tb[4*k+1] = fmaxf(v.y, EPSC) * inv;
      tb[4*k+2] = fmaxf(v.z, EPSC) * inv;
      tb[4*k+3] = fmaxf(v.w, EPSC) * inv;
    }
  }

  // ---- alpha~_0 = prior_norm * exp(em_0), lane-local, replicated across waves ----
  float2 pv = ((const float2*)prior)[lane];
  float p0v = fmaxf(pv.x, EPSC), p1v = fmaxf(pv.y, EPSC);
  float psum = p0v + p1v;
  #pragma unroll
  for (int m = 1; m < 64; m <<= 1) psum += __shfl_xor(psum, m, 64);
  const float pinv = rcpf(psum);
  float2 e0 = em2[lane];
  float a0 = p0v * pinv * __expf(e0.x);
  float a1 = p1v * pinv * __expf(e0.y);
  if (w == 0) out2[lane] = make_float2(a0, a1);

  // em pipeline: d = exp(em[t]) ready at iteration t; em_hold = em[t+1]
  float2 emA = em2[64 + lane];        // em[1]
  float2 em_hold = em2[128 + lane];   // em[2]
  float d0 = __expf(emA.x), d1 = __expf(emA.y);
  float rinv_last = 1.f;

  // ================= forward =================
  for (int t = 1; t < TT; ++t) {
    const float c = (h == 0) ? dot_half<0>(tf, a0, a1) : dot_half<32>(tf, a0, a1);
    const int buf = t & 1;
    part[buf][pr_][h * 68 + lane] = c;
    // off-chain prefetch
    const int tp = (t + 2 < TT) ? t + 2 : TT - 1;
    float2 em_pf = em2[tp * 64 + lane];
    __syncthreads();
    float2 pA = *(const float2*)&part[buf][ps][sl];
    float2 pB = *(const float2*)&part[buf][ps][68 + sl];
    const float raw0 = part[buf][0][0] + part[buf][0][68];
    const float rinv = rcpf(raw0);
    if (tid == 0) sarr[t] = rinv;
    rinv_last = rinv;
    a0 = (pA.x + pB.x) * (d0 * rinv);
    a1 = (pA.y + pB.y) * (d1 * rinv);
    if (w == 0 && t < TT - 1) out2[t * 64 + lane] = make_float2(a0, a1);
    d0 = __expf(em_hold.x); d1 = __expf(em_hold.y);   // d_{t+1}, off-chain
    em_hold = em_pf;
  }
  // post-loop: d0,d1 = exp(em[TT-1]) = d_{T-1}; rinv_last = r_{TT-1}

  // ================= final softmax (in-wave, replicated) =================
  float tot = a0 + a1;
  #pragma unroll
  for (int m = 1; m < 64; m <<= 1) tot += __shfl_xor(tot, m, 64);
  const float it = rcpf(tot);
  float q0 = a0 * it, q1 = a1 * it;                 // p_{T-1}
  if (w == 0) out2[(TT - 1) * 64 + lane] = make_float2(q0, q1);

  // q for first backward dot: q = p_{T-1} * d_{T-1} * r_{T-1} / alpha~_{T-1}
  q0 = q0 * (d0 * rinv_last * rcpf(a0));
  q1 = q1 * (d1 * rinv_last * rcpf(a1));

  // backward prefetch pipeline
  float2 ec_cur = out2[(TT - 2) * 64 + lane];       // alpha~_{TT-2}
  float2 ec_nxt = out2[(TT - 3) * 64 + lane];       // alpha~_{TT-3}
  float2 emb_c  = em2[(TT - 2) * 64 + lane];        // em[TT-2]
  float2 emb_n  = em2[(TT - 3) * 64 + lane];        // em[TT-3]
  float db0 = __expf(emb_c.x), db1 = __expf(emb_c.y);
  float sr_c = sarr[TT - 2];                        // visible: barriers since fwd write

  // ================= backward =================
  for (int t = TT - 2; t >= 0; --t) {
    const float c = (h == 0) ? dot_half<0>(tb, q0, q1) : dot_half<32>(tb, q0, q1);
    const int buf = t & 1;
    part[buf][pr_][h * 68 + lane] = c;
    // off-chain: g for q_next (all inputs prefetched)
    const float g0 = db0 * sr_c * rcpf(ec_cur.x);
    const float g1 = db1 * sr_c * rcpf(ec_cur.y);
    const int tp = (t >= 2) ? t - 2 : 0;
    float2 ec_pf = out2[tp * 64 + lane];
    float2 em_pf = em2[tp * 64 + lane];
    const int ts = (t >= 1) ? t - 1 : 0;
    const float sr_n = sarr[ts];
    __syncthreads();
    float2 pA = *(const float2*)&part[buf][ps][sl];
    float2 pB = *(const float2*)&part[buf][ps][68 + sl];
    const float p0 = ec_cur.x * (pA.x + pB.x);
    const float p1 = ec_cur.y * (pA.y + pB.y);
    if (w == 0) out2[t * 64 + lane] = make_float2(p0, p1);
    q0 = p0 * g0; q1 = p1 * g1;
    // rotate prefetch pipeline
    ec_cur = ec_nxt; ec_nxt = ec_pf;
    db0 = __expf(emb_n.x); db1 = __expf(emb_n.y);
    emb_n = em_pf;
    sr_c = sr_n;
  }
}

extern "C" void kernel_launch(void* const* d_in, const int* in_sizes, int n_in,
                              void* d_out, int out_size, void* d_ws, size_t ws_size,
                              hipStream_t stream) {
  (void)in_sizes; (void)n_in; (void)d_ws; (void)ws_size; (void)out_size;
  const float* trans = (const float*)d_in[0];
  const float* emis  = (const float*)d_in[1];
  const float* prior = (const float*)d_in[2];
  float* out = (float*)d_out;
  soft_viterbi_kernel<<<dim3(BB), dim3(256), 0, stream>>>(trans, emis, prior, out);
}